// Round 4
// baseline (2352.762 us; speedup 1.0000x reference)
//
#include <hip/hip_runtime.h>

#define PI_F 3.14159265358979323846f

#define NCH   1000
#define NPTS  30000
#define NHALF 15000      // NPTS/2 packed complex samples
#define NFFT  32768      // complex FFT length (real length 65536)
#define NBF32 1024       // butterflies per channel per radix-32 pass (NFFT/32)
#define STR   32770      // per-channel stride in complex elements
#define XCOR  59999

__device__ __forceinline__ float2 cadd(float2 a, float2 b){ return make_float2(a.x+b.x, a.y+b.y); }
__device__ __forceinline__ float2 csub(float2 a, float2 b){ return make_float2(a.x-b.x, a.y-b.y); }
__device__ __forceinline__ float2 cmul(float2 a, float2 b){ return make_float2(a.x*b.x - a.y*b.y, a.x*b.y + a.y*b.x); }

template<int S>
__device__ __forceinline__ float2 mulIs(float2 z){ return make_float2(-(float)S*z.y, (float)S*z.x); }

// 8-point DFT, ω = e^{S*2πi/8}
template<int S>
__device__ __forceinline__ void dft8(float2 v[8]){
  const float r2 = 0.7071067811865476f;
  const float sf = (float)S;
  float2 ea=cadd(v[0],v[4]), eb=csub(v[0],v[4]);
  float2 ec=cadd(v[2],v[6]), ed=csub(v[2],v[6]);
  float2 oa=cadd(v[1],v[5]), ob=csub(v[1],v[5]);
  float2 oc=cadd(v[3],v[7]), od=csub(v[3],v[7]);
  float2 ied=mulIs<S>(ed), iod=mulIs<S>(od);
  float2 E0=cadd(ea,ec), E2=csub(ea,ec), E1=cadd(eb,ied), E3=csub(eb,ied);
  float2 O0=cadd(oa,oc), O2=csub(oa,oc), O1=cadd(ob,iod), O3=csub(ob,iod);
  float2 T1 = make_float2(r2*(O1.x - sf*O1.y), r2*(O1.y + sf*O1.x));
  float2 T2 = mulIs<S>(O2);
  float2 T3 = make_float2(r2*(-O3.x - sf*O3.y), r2*(sf*O3.x - O3.y));
  v[0]=cadd(E0,O0); v[4]=csub(E0,O0);
  v[1]=cadd(E1,T1); v[5]=csub(E1,T1);
  v[2]=cadd(E2,T2); v[6]=csub(E2,T2);
  v[3]=cadd(E3,T3); v[7]=csub(E3,T3);
}

template<int S>
__device__ __forceinline__ void dft4(float2 v[4]){
  float2 t0=cadd(v[0],v[2]), t1=csub(v[0],v[2]);
  float2 t2=cadd(v[1],v[3]), t3=mulIs<S>(csub(v[1],v[3]));
  v[0]=cadd(t0,t2); v[2]=csub(t0,t2);
  v[1]=cadd(t1,t3); v[3]=csub(t1,t3);
}

// 32-point DFT in registers
template<int S>
__device__ __forceinline__ void dft32(float2 v[32]){
  constexpr float TC[22] = {
    1.f, 0.98078528040323044f, 0.92387953251128674f, 0.83146961230254524f,
    0.70710678118654757f, 0.55557023301960218f, 0.38268343236508978f, 0.19509032201612825f,
    0.f, -0.19509032201612825f, -0.38268343236508978f, -0.55557023301960218f,
    -0.70710678118654757f, -0.83146961230254524f, -0.92387953251128674f, -0.98078528040323044f,
    -1.f, -0.98078528040323044f, -0.92387953251128674f, -0.83146961230254524f,
    -0.70710678118654757f, -0.55557023301960218f };
  constexpr float TS[22] = {
    0.f, 0.19509032201612825f, 0.38268343236508978f, 0.55557023301960218f,
    0.70710678118654757f, 0.83146961230254524f, 0.92387953251128674f, 0.98078528040323044f,
    1.f, 0.98078528040323044f, 0.92387953251128674f, 0.83146961230254524f,
    0.70710678118654757f, 0.55557023301960218f, 0.38268343236508978f, 0.19509032201612825f,
    0.f, -0.19509032201612825f, -0.38268343236508978f, -0.55557023301960218f,
    -0.70710678118654757f, -0.83146961230254524f };
  float2 y[4][8];
  #pragma unroll
  for (int b = 0; b < 4; ++b)
    #pragma unroll
    for (int a = 0; a < 8; ++a) y[b][a] = v[4*a + b];
  #pragma unroll
  for (int b = 0; b < 4; ++b) dft8<S>(y[b]);
  #pragma unroll
  for (int b = 1; b < 4; ++b)
    #pragma unroll
    for (int k1 = 1; k1 < 8; ++k1) {
      int m = b*k1;
      float2 w = make_float2(TC[m], (float)S * TS[m]);
      y[b][k1] = cmul(y[b][k1], w);
    }
  #pragma unroll
  for (int k1 = 0; k1 < 8; ++k1) {
    float2 z[4] = { y[0][k1], y[1][k1], y[2][k1], y[3][k1] };
    dft4<S>(z);
    #pragma unroll
    for (int k2 = 0; k2 < 4; ++k2) v[k1 + 8*k2] = z[k2];
  }
}

template<int S>
__device__ __forceinline__ void stage_twiddle32(float2 v[32], float ang){
  float s1,c1,s8,c8;
  __sincosf(ang, &s1, &c1);
  __sincosf(8.f*ang, &s8, &c8);
  float2 w1 = make_float2(c1, s1), w8 = make_float2(c8, s8);
  float2 w16 = cmul(w8, w8), w24 = cmul(w16, w8);
  float2 base[4] = { make_float2(1.f, 0.f), w8, w16, w24 };
  #pragma unroll
  for (int m = 0; m < 4; ++m) {
    float2 wr = base[m];
    if (m > 0) v[8*m] = cmul(v[8*m], wr);
    #pragma unroll
    for (int l = 1; l < 8; ++l) { wr = cmul(wr, w1); v[8*m+l] = cmul(v[8*m+l], wr); }
  }
}

// ---------- forward pass 1 (Ns=1, radix-32), fused with real-pair packing + zero pad ----------
__global__ __launch_bounds__(256) void fft_fwd_p1_r32(const float* __restrict__ d1, const float* __restrict__ d2,
                                                      float2* __restrict__ out, int cb, int ch0)
{
  int tid = blockIdx.x*256 + threadIdx.x;
  int c = tid >> 10;
  int j = tid & (NBF32-1);
  const float* src = (c < cb) ? (d1 + (size_t)(ch0 + c) * NPTS)
                              : (d2 + (size_t)(ch0 + c - cb) * NPTS);
  const float2* src2 = reinterpret_cast<const float2*>(src);
  float2 v[32];
  #pragma unroll
  for (int r = 0; r < 32; ++r) {
    int m = j + (r << 10);
    v[r] = (m < NHALF) ? src2[m] : make_float2(0.f, 0.f);
  }
  dft32<-1>(v);
  float2* dst = out + (size_t)c * STR + (size_t)j * 32;
  #pragma unroll
  for (int r = 0; r < 32; r += 2)
    *reinterpret_cast<float4*>(dst + r) = make_float4(v[r].x, v[r].y, v[r+1].x, v[r+1].y);
}

// ---------- generic Stockham radix-32 pass, Ns = 2^LG ----------
template<int LG, int S>
__global__ __launch_bounds__(256) void fft_pass32(const float2* __restrict__ in, float2* __restrict__ out)
{
  int tid = blockIdx.x*256 + threadIdx.x;
  int c = tid >> 10;
  int j = tid & (NBF32-1);
  const float2* src = in + (size_t)c * STR;
  float2 v[32];
  #pragma unroll
  for (int r = 0; r < 32; ++r) v[r] = src[j + (r << 10)];
  constexpr int NS = 1 << LG;
  int jm = j & (NS - 1);
  if constexpr (LG > 0) {
    float ang = (float)S * (2.0f*PI_F) * (float)jm / (float)(NS*32);
    stage_twiddle32<S>(v, ang);
  }
  dft32<S>(v);
  int idxD = ((j >> LG) << (LG+5)) + jm;
  float2* dst = out + (size_t)c * STR + idxD;
  #pragma unroll
  for (int r = 0; r < 32; ++r) dst[(size_t)(r << LG)] = v[r];
}

// ================= MEGA2 =================
// Per channel (1024 threads): final fwd stage + rfft-unpack + whiten for BOTH arrays
// (array 1's whitened spectrum parked in global slot-layout buffer), then
// cross-spectrum + irfft-pack + inverse pass (Ns=1) fused, all same-thread.
// Slot map after unpack: v[i] (i<16) = X[i*1024+t]; v[c] (c>=16) = X[c*1024+e0],
// e0 = (t==0)?1024:1024-t. X[16384] in dedicated reg (t==0).

__device__ __forceinline__ int padidx(int m){ return m + (m >> 5); }

__device__ __forceinline__ float smooth_at(int k, const float* s, float a0, float alast){
  int hi = k + 327; if (hi > 32768) hi = 32768;
  int lo = k - 328;
  float Shi = s[padidx(hi)];
  float Slo = (lo >= 0) ? s[padidx(lo)] : 0.f;
  float lc = (k < 327) ? (float)(327 - k) : 0.f;
  float rc = (k > 32441) ? (float)(k - 32441) : 0.f;
  return (lc*a0 + (Shi - Slo) + rc*alast) * (1.0f/655.0f);
}

template<bool STORE>
__device__ __forceinline__ void whiten_one_g(const float2* __restrict__ src,
                                             float2* __restrict__ wout,
                                             int t, int lane, int wid,
                                             float* s, float* wt, float2* t0ext,
                                             float2 v[32], float2& X16)
{
  float2* ex = reinterpret_cast<float2*>(s);
  // ---- load + final forward radix-32 stage (LG=10) ----
  #pragma unroll
  for (int r = 0; r < 32; ++r) v[r] = src[t + (r << 10)];
  stage_twiddle32<-1>(v, -(2.0f*PI_F) * (float)t * (1.0f/32768.0f));
  dft32<-1>(v);

  if (t == 0) {
    t0ext[0] = v[0];
    #pragma unroll
    for (int i = 1; i < 16; ++i) t0ext[i] = v[32 - i];
    X16 = make_float2(v[16].x, -v[16].y);   // X[16384] = conj(Z[16384])
  }

  const float2 wstep = make_float2(0.99518472667219693f, -0.09801714032956060f); // e^{-i pi/32}
  float s0, c0; __sincosf(-PI_F*(float)t*(1.0f/32768.0f), &s0, &c0);
  float2 wcur = make_float2(c0, s0);

  __syncthreads();   // guard: previous use of s finished
  // ---- round A: exchange chunks 24..31, unpack i=0..7 ----
  #pragma unroll
  for (int cc = 24; cc < 32; ++cc) ex[((cc-24)<<10) + t] = v[cc];
  __syncthreads();
  #pragma unroll
  for (int i = 0; i < 8; ++i) {
    int cm = 31 - i;
    float2 zn = (t == 0) ? t0ext[i] : ex[((cm-24)<<10) + (1024 - t)];
    float2 zk = v[i];
    float2 xe = make_float2(0.5f*(zk.x+zn.x), 0.5f*(zk.y-zn.y));
    float2 xh = make_float2(0.5f*(zk.x-zn.x), 0.5f*(zk.y+zn.y));
    float2 xo = make_float2(xh.y, -xh.x);
    float2 p  = cmul(wcur, xo);
    v[i]  = cadd(xe, p);
    v[cm] = make_float2(xe.x - p.x, -(xe.y - p.y));
    wcur = cmul(wcur, wstep);
  }
  __syncthreads();
  // ---- round B: exchange chunks 16..23, unpack i=8..15 ----
  #pragma unroll
  for (int cc = 16; cc < 24; ++cc) ex[((cc-16)<<10) + t] = v[cc];
  __syncthreads();
  #pragma unroll
  for (int i = 8; i < 16; ++i) {
    int cm = 31 - i;
    float2 zn = (t == 0) ? t0ext[i] : ex[((cm-16)<<10) + (1024 - t)];
    float2 zk = v[i];
    float2 xe = make_float2(0.5f*(zk.x+zn.x), 0.5f*(zk.y-zn.y));
    float2 xh = make_float2(0.5f*(zk.x-zn.x), 0.5f*(zk.y+zn.y));
    float2 xo = make_float2(xh.y, -xh.x);
    float2 p  = cmul(wcur, xo);
    v[i]  = cadd(xe, p);
    v[cm] = make_float2(xe.x - p.x, -(xe.y - p.y));
    wcur = cmul(wcur, wstep);
  }
  __syncthreads();

  // ---- magnitudes -> s[] (padidx layout) ----
  #pragma unroll
  for (int i = 0; i < 16; ++i) { float2 a = v[i]; s[padidx((i<<10) + t)] = sqrtf(a.x*a.x + a.y*a.y); }
  if (t != 0) {
    #pragma unroll
    for (int cc = 16; cc < 32; ++cc) { float2 a = v[cc]; s[padidx((cc<<10) + (1024 - t))] = sqrtf(a.x*a.x + a.y*a.y); }
  } else {
    #pragma unroll
    for (int cc = 16; cc < 32; ++cc) { float2 a = v[cc]; s[padidx((cc+1)<<10)] = sqrtf(a.x*a.x + a.y*a.y); }
    { float2 a = X16; s[padidx(16384)] = sqrtf(a.x*a.x + a.y*a.y); }
  }
  __syncthreads();

  // ---- VGPR-light chunk scan (inclusive cumsum in place) ----
  const int base = t << 5;
  float sum = 0.f;
  #pragma unroll
  for (int q = 0; q < 32; ++q) sum += s[padidx(base+q)];
  if (t == 1023) sum += s[padidx(32768)];
  float vv = sum;
  #pragma unroll
  for (int off = 1; off < 64; off <<= 1) {
    float u = __shfl_up(vv, off);
    if (lane >= off) vv += u;
  }
  if (lane == 63) wt[wid] = vv;
  __syncthreads();
  float wexcl = 0.f;
  #pragma unroll
  for (int w = 0; w < 16; ++w) wexcl += (w < wid) ? wt[w] : 0.f;
  float run = wexcl + (vv - sum);
  #pragma unroll
  for (int q = 0; q < 32; ++q) { int idx = padidx(base+q); run += s[idx]; s[idx] = run; }
  if (t == 1023) { int idx = padidx(32768); run += s[idx]; s[idx] = run; }
  __syncthreads();

  // ---- whiten + taper (W kept in v[]) ----
  float a0 = s[padidx(0)];
  float alast = s[padidx(32768)] - s[padidx(32767)];
  #pragma unroll
  for (int i = 0; i < 16; ++i) {
    int k = (i<<10) + t;
    float sm = smooth_at(k, s, a0, alast);
    float tp = 1.0f;
    if (k < 131)        { float th = (float)k * (PI_F/260.0f);           float sn2 = __sinf(th); tp = sn2*sn2; }
    else if (k >= 13108){ float th = (float)(k-13108) * (PI_F/39320.0f); float cs2 = __cosf(th); tp = cs2*cs2; }
    float g = (sm > 0.f) ? tp / sm : 0.f;
    v[i] = make_float2(v[i].x*g, v[i].y*g);
  }
  int e0 = (t == 0) ? 1024 : (1024 - t);
  #pragma unroll
  for (int cc = 16; cc < 32; ++cc) {
    int k = (cc<<10) + e0;                 // all >= 16385 > 13108
    float sm = smooth_at(k, s, a0, alast);
    float th = (float)(k-13108) * (PI_F/39320.0f); float cs2 = __cosf(th);
    float g = (sm > 0.f) ? (cs2*cs2) / sm : 0.f;
    v[cc] = make_float2(v[cc].x*g, v[cc].y*g);
  }
  if (t == 0) {
    float sm = smooth_at(16384, s, a0, alast);
    float ct = __cosf(3276.0f * (PI_F/39320.0f));
    float g = (sm > 0.f) ? (ct*ct) / sm : 0.f;
    X16 = make_float2(X16.x*g, X16.y*g);
  }

  if constexpr (STORE) {
    // park W in global, slot layout (same-thread readback later; fully coalesced)
    float4* o4 = reinterpret_cast<float4*>(wout + (size_t)t * 32);
    #pragma unroll
    for (int r = 0; r < 32; r += 2)
      o4[r>>1] = make_float4(v[r].x, v[r].y, v[r+1].x, v[r+1].y);
    if (t == 0) wout[32768] = X16;
  }
}

__global__ __launch_bounds__(1024, 4) void mega2(const float2* __restrict__ in,
                                                 float2* __restrict__ w1buf,
                                                 float2* __restrict__ out0,
                                                 int cb)
{
  const int c = blockIdx.x;
  const int t = threadIdx.x;
  const int lane = t & 63, wid = t >> 6;

  __shared__ __align__(16) float s[33793];   // 135 KB: mags/cumsum; aliased as exchange buf
  __shared__ float wt[16];
  __shared__ float2 t0ext[16];

  const float2* src1 = in + (size_t)c * STR;
  const float2* src2 = in + (size_t)(cb + c) * STR;
  float2* w1g = w1buf + (size_t)c * STR;

  float2 v[32];
  float2 X16_1 = make_float2(0.f, 0.f), X16_2 = make_float2(0.f, 0.f);

  whiten_one_g<true >(src1, w1g, t, lane, wid, s, wt, t0ext, v, X16_1);
  whiten_one_g<false>(src2, nullptr, t, lane, wid, s, wt, t0ext, v, X16_2);

  // ---- cross C = conj(W1)*W2, irfft pack, + inverse pass Ns=1 (fused) ----
  __syncthreads();                       // s -> lds2 reuse
  float2* lds2 = reinterpret_cast<float2*>(s);   // 16 chunks x 1024 float2 = 128 KB
  float ps_, pc_; __sincosf(PI_F*(float)t*(1.0f/32768.0f), &ps_, &pc_);
  float2 pw = make_float2(pc_, ps_);
  const float2 pstep = make_float2(0.99518472667219693f, 0.09801714032956060f); // e^{+i pi/32}
  const float scale = 1.0f/32768.0f;
  #pragma unroll
  for (int i = 0; i < 16; ++i) {
    int k = (i<<10) + t;
    float2 A  = w1g[(size_t)t*32 + i];
    float2 Am = w1g[(size_t)t*32 + 31 - i];
    float2 B  = v[i], Bm = v[31-i];
    float2 Ck = make_float2(A.x*B.x + A.y*B.y,     A.x*B.y - A.y*B.x);
    float2 Cm = make_float2(Am.x*Bm.x + Am.y*Bm.y, Am.x*Bm.y - Am.y*Bm.x);
    float cs = pw.x, sn = pw.y;
    float2 zk, zm;
    {
      float2 xe = make_float2(0.5f*(Ck.x+Cm.x), 0.5f*(Ck.y-Cm.y));
      float2 d  = make_float2(0.5f*(Ck.x-Cm.x), 0.5f*(Ck.y+Cm.y));
      float2 xo = cmul(make_float2(cs, sn), d);
      zk = make_float2((xe.x - xo.y)*scale, (xe.y + xo.x)*scale);
    }
    {
      float2 xe = make_float2(0.5f*(Cm.x+Ck.x), 0.5f*(Cm.y-Ck.y));
      float2 d  = make_float2(0.5f*(Cm.x-Ck.x), 0.5f*(Cm.y+Ck.y));
      float2 xo = cmul(make_float2(-cs, sn), d);
      zm = make_float2((xe.x - xo.y)*scale, (xe.y + xo.x)*scale);
    }
    v[i] = zk;                                       // Zinv[i*1024+t] stays in-reg
    // mirror Zinv[32768-k] -> chunk 31-i (local 15-i), elem 1024-t
    if (t != 0)      lds2[((15-i)<<10) + (1024 - t)] = zm;
    else if (i != 0) lds2[(16-i)<<10] = zm;          // t==0: chunk 32-i elem 0 (skip i==0: bin 32768)
    pw = cmul(pw, pstep);
  }
  if (t == 0) {
    float2 A = w1g[32768], B = X16_2;
    float2 C16 = make_float2(A.x*B.x + A.y*B.y, A.x*B.y - A.y*B.x);
    lds2[0] = make_float2(C16.x*scale, -C16.y*scale);   // Zinv[16384] = conj(C16)/N; chunk 16 local 0
  }
  __syncthreads();
  #pragma unroll
  for (int q = 0; q < 16; ++q) v[16+q] = lds2[(q<<10) + t];
  // inverse Stockham pass Ns=1 (no twiddle): out[32t + r] = dft32(v)[r]
  dft32<1>(v);
  float4* o4 = reinterpret_cast<float4*>(out0 + (size_t)c * STR + (size_t)t * 32);
  #pragma unroll
  for (int r = 0; r < 32; r += 2)
    o4[r>>1] = make_float4(v[r].x, v[r].y, v[r+1].x, v[r+1].y);
}

// ---------- inverse final pass (Ns=1024, radix-32), fused unpack + roll + slice ----------
__global__ __launch_bounds__(256) void fft_inv_final32(const float2* __restrict__ in, float* __restrict__ out, int ch0)
{
  int tid = blockIdx.x*256 + threadIdx.x;
  int c = tid >> 10;
  int j = tid & (NBF32-1);
  const float2* src = in + (size_t)c * STR;
  float2 v[32];
  #pragma unroll
  for (int r = 0; r < 32; ++r) v[r] = src[j + (r << 10)];
  float ang = (2.0f*PI_F) * (float)j * (1.0f/32768.0f);
  stage_twiddle32<1>(v, ang);
  dft32<1>(v);
  float* o = out + (size_t)(ch0 + c) * XCOR;
  #pragma unroll
  for (int r = 0; r < 32; ++r) {
    int n = j + (r << 10);
    int m = 2*n;
    int j1 = (m <= 29999) ? (m + 29999) : ((m >= 35537) ? (m - 35537) : -1);
    if (j1 >= 0) o[j1] = v[r].x;
    int m2 = m + 1;
    int j2 = (m2 <= 29999) ? (m2 + 29999) : ((m2 >= 35537) ? (m2 - 35537) : -1);
    if (j2 >= 0) o[j2] = v[r].y;
  }
}

__global__ void diag_kernel(float* out, float vv){ if (threadIdx.x==0 && blockIdx.x==0) out[0] = vv; }

extern "C" void kernel_launch(void* const* d_in, const int* in_sizes, int n_in,
                              void* d_out, int out_size, void* d_ws, size_t ws_size,
                              hipStream_t stream)
{
  const float* d1 = (const float*)d_in[0];
  const float* d2 = (const float*)d_in[1];
  float* out = (float*)d_out;

  const size_t bytesPerCh = 2ULL * 2ULL * (size_t)STR * sizeof(float2);
  int CB = (int)(ws_size / bytesPerCh);
  if (CB > NCH) CB = NCH;
  if (CB < 1) { diag_kernel<<<1,1,0,stream>>>(out, (float)ws_size); return; }

  float2* bufA = (float2*)d_ws;
  float2* bufB = bufA + (size_t)2 * CB * STR;

  for (int ch0 = 0; ch0 < NCH; ch0 += CB) {
    int cb = (NCH - ch0 < CB) ? (NCH - ch0) : CB;
    int nch2 = 2*cb;
    dim3 thr(256);

    // forward FFT stages 1,2 (both arrays batched): A -> B
    fft_fwd_p1_r32    <<<dim3(nch2*4), thr, 0, stream>>>(d1, d2, bufA, cb, ch0);
    fft_pass32<5,-1>  <<<dim3(nch2*4), thr, 0, stream>>>(bufA, bufB);

    // fused: final fwd stage + unpack + whiten (x2) + cross + irfft pack + inv pass Ns=1
    // reads B; W1 parked in A[cb..2cb); inv-pass0 output -> A[0..cb)
    mega2             <<<dim3(cb), dim3(1024), 0, stream>>>(bufB, bufA + (size_t)cb * STR, bufA, cb);

    // inverse FFT: middle pass + final (fused roll+slice)
    fft_pass32<5,1>   <<<dim3(cb*4), thr, 0, stream>>>(bufA, bufB);
    fft_inv_final32   <<<dim3(cb*4), thr, 0, stream>>>(bufB, out, ch0);
  }
}

// Round 5
// 1759.225 us; speedup vs baseline: 1.3374x; 1.3374x over previous
//
#include <hip/hip_runtime.h>

#define PI_F 3.14159265358979323846f

#define NCH   1000
#define NPTS  30000
#define NHALF 15000      // NPTS/2 packed complex samples
#define NFFT  32768      // complex FFT length (real length 65536)
#define NBF32 1024       // butterflies per channel per radix-32 pass (NFFT/32)
#define STR   32770      // per-channel stride in complex elements
#define XCOR  59999

__device__ __forceinline__ float2 cadd(float2 a, float2 b){ return make_float2(a.x+b.x, a.y+b.y); }
__device__ __forceinline__ float2 csub(float2 a, float2 b){ return make_float2(a.x-b.x, a.y-b.y); }
__device__ __forceinline__ float2 cmul(float2 a, float2 b){ return make_float2(a.x*b.x - a.y*b.y, a.x*b.y + a.y*b.x); }

template<int S>
__device__ __forceinline__ float2 mulIs(float2 z){ return make_float2(-(float)S*z.y, (float)S*z.x); }

// 8-point DFT, ω = e^{S*2πi/8}
template<int S>
__device__ __forceinline__ void dft8(float2 v[8]){
  const float r2 = 0.7071067811865476f;
  const float sf = (float)S;
  float2 ea=cadd(v[0],v[4]), eb=csub(v[0],v[4]);
  float2 ec=cadd(v[2],v[6]), ed=csub(v[2],v[6]);
  float2 oa=cadd(v[1],v[5]), ob=csub(v[1],v[5]);
  float2 oc=cadd(v[3],v[7]), od=csub(v[3],v[7]);
  float2 ied=mulIs<S>(ed), iod=mulIs<S>(od);
  float2 E0=cadd(ea,ec), E2=csub(ea,ec), E1=cadd(eb,ied), E3=csub(eb,ied);
  float2 O0=cadd(oa,oc), O2=csub(oa,oc), O1=cadd(ob,iod), O3=csub(ob,iod);
  float2 T1 = make_float2(r2*(O1.x - sf*O1.y), r2*(O1.y + sf*O1.x));
  float2 T2 = mulIs<S>(O2);
  float2 T3 = make_float2(r2*(-O3.x - sf*O3.y), r2*(sf*O3.x - O3.y));
  v[0]=cadd(E0,O0); v[4]=csub(E0,O0);
  v[1]=cadd(E1,T1); v[5]=csub(E1,T1);
  v[2]=cadd(E2,T2); v[6]=csub(E2,T2);
  v[3]=cadd(E3,T3); v[7]=csub(E3,T3);
}

template<int S>
__device__ __forceinline__ void dft4(float2 v[4]){
  float2 t0=cadd(v[0],v[2]), t1=csub(v[0],v[2]);
  float2 t2=cadd(v[1],v[3]), t3=mulIs<S>(csub(v[1],v[3]));
  v[0]=cadd(t0,t2); v[2]=csub(t0,t2);
  v[1]=cadd(t1,t3); v[3]=csub(t1,t3);
}

// 32-point DFT in registers
template<int S>
__device__ __forceinline__ void dft32(float2 v[32]){
  constexpr float TC[22] = {
    1.f, 0.98078528040323044f, 0.92387953251128674f, 0.83146961230254524f,
    0.70710678118654757f, 0.55557023301960218f, 0.38268343236508978f, 0.19509032201612825f,
    0.f, -0.19509032201612825f, -0.38268343236508978f, -0.55557023301960218f,
    -0.70710678118654757f, -0.83146961230254524f, -0.92387953251128674f, -0.98078528040323044f,
    -1.f, -0.98078528040323044f, -0.92387953251128674f, -0.83146961230254524f,
    -0.70710678118654757f, -0.55557023301960218f };
  constexpr float TS[22] = {
    0.f, 0.19509032201612825f, 0.38268343236508978f, 0.55557023301960218f,
    0.70710678118654757f, 0.83146961230254524f, 0.92387953251128674f, 0.98078528040323044f,
    1.f, 0.98078528040323044f, 0.92387953251128674f, 0.83146961230254524f,
    0.70710678118654757f, 0.55557023301960218f, 0.38268343236508978f, 0.19509032201612825f,
    0.f, -0.19509032201612825f, -0.38268343236508978f, -0.55557023301960218f,
    -0.70710678118654757f, -0.83146961230254524f };
  float2 y[4][8];
  #pragma unroll
  for (int b = 0; b < 4; ++b)
    #pragma unroll
    for (int a = 0; a < 8; ++a) y[b][a] = v[4*a + b];
  #pragma unroll
  for (int b = 0; b < 4; ++b) dft8<S>(y[b]);
  #pragma unroll
  for (int b = 1; b < 4; ++b)
    #pragma unroll
    for (int k1 = 1; k1 < 8; ++k1) {
      int m = b*k1;
      float2 w = make_float2(TC[m], (float)S * TS[m]);
      y[b][k1] = cmul(y[b][k1], w);
    }
  #pragma unroll
  for (int k1 = 0; k1 < 8; ++k1) {
    float2 z[4] = { y[0][k1], y[1][k1], y[2][k1], y[3][k1] };
    dft4<S>(z);
    #pragma unroll
    for (int k2 = 0; k2 < 4; ++k2) v[k1 + 8*k2] = z[k2];
  }
}

template<int S>
__device__ __forceinline__ void stage_twiddle32(float2 v[32], float ang){
  float s1,c1,s8,c8;
  __sincosf(ang, &s1, &c1);
  __sincosf(8.f*ang, &s8, &c8);
  float2 w1 = make_float2(c1, s1), w8 = make_float2(c8, s8);
  float2 w16 = cmul(w8, w8), w24 = cmul(w16, w8);
  float2 base[4] = { make_float2(1.f, 0.f), w8, w16, w24 };
  #pragma unroll
  for (int m = 0; m < 4; ++m) {
    float2 wr = base[m];
    if (m > 0) v[8*m] = cmul(v[8*m], wr);
    #pragma unroll
    for (int l = 1; l < 8; ++l) { wr = cmul(wr, w1); v[8*m+l] = cmul(v[8*m+l], wr); }
  }
}

// ---------- forward pass 1 (Ns=1, radix-32), fused with real-pair packing + zero pad ----------
__global__ __launch_bounds__(256) void fft_fwd_p1_r32(const float* __restrict__ d1, const float* __restrict__ d2,
                                                      float2* __restrict__ out, int cb, int ch0)
{
  int tid = blockIdx.x*256 + threadIdx.x;
  int c = tid >> 10;
  int j = tid & (NBF32-1);
  const float* src = (c < cb) ? (d1 + (size_t)(ch0 + c) * NPTS)
                              : (d2 + (size_t)(ch0 + c - cb) * NPTS);
  const float2* src2 = reinterpret_cast<const float2*>(src);
  float2 v[32];
  #pragma unroll
  for (int r = 0; r < 32; ++r) {
    int m = j + (r << 10);
    v[r] = (m < NHALF) ? src2[m] : make_float2(0.f, 0.f);
  }
  dft32<-1>(v);
  float2* dst = out + (size_t)c * STR + (size_t)j * 32;
  #pragma unroll
  for (int r = 0; r < 32; r += 2)
    *reinterpret_cast<float4*>(dst + r) = make_float4(v[r].x, v[r].y, v[r+1].x, v[r+1].y);
}

// ---------- generic Stockham radix-32 pass, Ns = 2^LG ----------
template<int LG, int S>
__global__ __launch_bounds__(256) void fft_pass32(const float2* __restrict__ in, float2* __restrict__ out)
{
  int tid = blockIdx.x*256 + threadIdx.x;
  int c = tid >> 10;
  int j = tid & (NBF32-1);
  const float2* src = in + (size_t)c * STR;
  float2 v[32];
  #pragma unroll
  for (int r = 0; r < 32; ++r) v[r] = src[j + (r << 10)];
  constexpr int NS = 1 << LG;
  int jm = j & (NS - 1);
  if constexpr (LG > 0) {
    float ang = (float)S * (2.0f*PI_F) * (float)jm / (float)(NS*32);
    stage_twiddle32<S>(v, ang);
  }
  dft32<S>(v);
  int idxD = ((j >> LG) << (LG+5)) + jm;
  float2* dst = out + (size_t)c * STR + idxD;
  #pragma unroll
  for (int r = 0; r < 32; ++r) dst[(size_t)(r << LG)] = v[r];
}

// ================= WHITEN3: final fwd stage + rfft-unpack + running-abs-mean + taper =================
// One block = one (array,channel). Thread t = final-stage butterfly t: holds Z[t+1024r] (64 VGPR).
// Pairs (k=1024i+t, 32768-k) share unpack products; mirror F-values via 24KB LDS exchange (6 rounds,
// descending i = 15..0). X never held across the scan: recomputed in phase B from held Z + re-exchange.

__device__ __forceinline__ int padidx(int m){ return m + (m >> 5); }

__device__ __forceinline__ float smooth_at(int k, const float* s, float a0, float alast){
  int hi = k + 327; if (hi > 32768) hi = 32768;
  int lo = k - 328;
  float Shi = s[padidx(hi)];
  float Slo = (lo >= 0) ? s[padidx(lo)] : 0.f;
  float lc = (k < 327) ? (float)(327 - k) : 0.f;
  float rc = (k > 32441) ? (float)(k - 32441) : 0.f;
  return (lc*a0 + (Shi - Slo) + rc*alast) * (1.0f/655.0f);
}

#define UC 0.99518472667219693f
#define US 0.09801714032956060f

__global__ __launch_bounds__(1024) __attribute__((amdgpu_waves_per_eu(4,4)))
void whiten3(float2* __restrict__ buf)
{
  const int t = threadIdx.x;
  const int lane = t & 63, wid = t >> 6;
  float2* Z = buf + (size_t)blockIdx.x * STR;

  __shared__ float s[33793];       // 132 KB mags -> cumsum (padded every 32)
  __shared__ float2 ex[3072];      // 24 KB mirror-slot exchange (3 chunks/round)
  __shared__ float wt[16];

  // ---- load + final forward radix-32 stage (LG=10): zn_[r] = F[t + 1024r] ----
  float2 zn_[32];
  #pragma unroll
  for (int r = 0; r < 32; ++r) zn_[r] = Z[t + (r << 10)];
  stage_twiddle32<-1>(zn_, -(2.0f*PI_F) * (float)t * (1.0f/32768.0f));
  dft32<-1>(zn_);

  // ================= phase A: magnitudes =================
  {
    // w(i) = e^{-i pi (1024 i + t)/32768}, consumed descending i=15..0: step e^{+i pi/32}
    float s0, c0; __sincosf(-PI_F*(15360.0f+(float)t)*(1.0f/32768.0f), &s0, &c0);
    float2 wcur = make_float2(c0, s0);
    const float2 wstep = make_float2(UC, US);
    #pragma unroll
    for (int g = 0; g < 6; ++g) {
      const int nsl = (g < 5) ? 3 : 1;
      #pragma unroll
      for (int q = 0; q < 3; ++q) if (q < nsl) ex[(q<<10) + t] = zn_[16 + 3*g + q];
      __syncthreads();
      #pragma unroll
      for (int q = 0; q < 3; ++q) if (q < nsl) {
        const int i = 15 - 3*g - q;          // mirror slot 31-i == 16+3g+q
        float2 zk = zn_[i];
        float2 zm = (t == 0) ? zn_[(32 - i) & 31] : ex[(q<<10) + (1024 - t)];
        float2 xe = make_float2(0.5f*(zk.x+zm.x), 0.5f*(zk.y-zm.y));
        float2 xh = make_float2(0.5f*(zk.x-zm.x), 0.5f*(zk.y+zm.y));
        float2 xo = make_float2(xh.y, -xh.x);
        float2 p  = cmul(wcur, xo);
        float2 Xn = cadd(xe, p);                       // X[1024 i + t]
        float2 Xm = csub(xe, p);                       // conj(X[32768-k]) -> same magnitude
        s[padidx((i<<10) + t)]        = sqrtf(Xn.x*Xn.x + Xn.y*Xn.y);
        s[padidx(((32-i)<<10) - t)]   = sqrtf(Xm.x*Xm.x + Xm.y*Xm.y);
        wcur = cmul(wcur, wstep);
      }
      __syncthreads();
    }
    if (t == 0) { float2 a = zn_[16]; s[padidx(16384)] = sqrtf(a.x*a.x + a.y*a.y); }
  }
  __syncthreads();

  // ================= scan: block-wide inclusive cumsum (chunk method) =================
  {
    const int base = t << 5;
    float sum = 0.f;
    #pragma unroll
    for (int q = 0; q < 32; ++q) sum += s[padidx(base+q)];
    if (t == 1023) sum += s[padidx(32768)];
    float vv = sum;
    #pragma unroll
    for (int off = 1; off < 64; off <<= 1) {
      float u = __shfl_up(vv, off);
      if (lane >= off) vv += u;
    }
    if (lane == 63) wt[wid] = vv;
    __syncthreads();
    float wexcl = 0.f;
    #pragma unroll
    for (int w = 0; w < 16; ++w) wexcl += (w < wid) ? wt[w] : 0.f;
    float run = wexcl + (vv - sum);
    #pragma unroll
    for (int q = 0; q < 32; ++q) { int idx = padidx(base+q); run += s[idx]; s[idx] = run; }
    if (t == 1023) { int idx = padidx(32768); run += s[idx]; s[idx] = run; }
  }
  __syncthreads();

  // ================= phase B: whiten + taper, write W =================
  {
    const float a0 = s[padidx(0)];
    const float alast = s[padidx(32768)] - s[padidx(32767)];
    float s0, c0;
    __sincosf(-PI_F*(15360.0f+(float)t)*(1.0f/32768.0f), &s0, &c0);
    float2 wcur = make_float2(c0, s0);
    const float2 wstep = make_float2(UC, US);
    // taper rotators: un for naturals (theta = pi(k-13108)/39320, k desc by 1024),
    //                 um for mirrors  (km asc by 1024)
    float tss, tcc; __sincosf(1024.0f*PI_F/39320.0f, &tss, &tcc);
    const float2 unstep = make_float2(tcc, -tss);
    const float2 umstep = make_float2(tcc,  tss);
    float us0, uc0;
    __sincosf((2252.0f+(float)t)*(PI_F/39320.0f), &us0, &uc0);          // k=15360+t
    float2 un = make_float2(uc0, us0);
    __sincosf((4300.0f-(float)t)*(PI_F/39320.0f), &us0, &uc0);          // km=17408-t
    float2 um = make_float2(uc0, us0);

    #pragma unroll
    for (int g = 0; g < 6; ++g) {
      const int nsl = (g < 5) ? 3 : 1;
      #pragma unroll
      for (int q = 0; q < 3; ++q) if (q < nsl) ex[(q<<10) + t] = zn_[16 + 3*g + q];
      __syncthreads();
      #pragma unroll
      for (int q = 0; q < 3; ++q) if (q < nsl) {
        const int i = 15 - 3*g - q;
        const int k = (i<<10) + t;
        const int km = ((32-i)<<10) - t;
        float2 zk = zn_[i];
        float2 zm = (t == 0) ? zn_[(32 - i) & 31] : ex[(q<<10) + (1024 - t)];
        float2 xe = make_float2(0.5f*(zk.x+zm.x), 0.5f*(zk.y-zm.y));
        float2 xh = make_float2(0.5f*(zk.x-zm.x), 0.5f*(zk.y+zm.y));
        float2 xo = make_float2(xh.y, -xh.x);
        float2 p  = cmul(wcur, xo);
        float2 Xn = cadd(xe, p);
        float2 Xm = make_float2(xe.x - p.x, -(xe.y - p.y));   // X[32768-k]
        // natural gain
        float smn = smooth_at(k, s, a0, alast);
        float tpn;
        if (i >= 13)      tpn = un.x*un.x;
        else if (i == 12) tpn = (t >= 820) ? un.x*un.x : 1.0f;
        else if (i == 0)  { if (t < 131) { float sn2 = __sinf((float)t * (PI_F/260.0f)); tpn = sn2*sn2; } else tpn = 1.0f; }
        else              tpn = 1.0f;
        float gn = (smn > 0.f) ? tpn / smn : 0.f;
        // mirror gain (km >= 16385 always -> cos^2 region)
        float smm = smooth_at(km, s, a0, alast);
        float gm = (smm > 0.f) ? (um.x*um.x) / smm : 0.f;
        Z[k]  = make_float2(Xn.x*gn, Xn.y*gn);
        Z[km] = make_float2(Xm.x*gm, Xm.y*gm);
        wcur = cmul(wcur, wstep);
        un = cmul(un, unstep);
        um = cmul(um, umstep);
      }
      __syncthreads();
    }
    if (t == 0) {
      float sm = smooth_at(16384, s, a0, alast);
      float ct = __cosf(3276.0f * (PI_F/39320.0f));
      float g = (sm > 0.f) ? (ct*ct) / sm : 0.f;
      float2 z16 = zn_[16];
      Z[16384] = make_float2(z16.x*g, -z16.y*g);   // conj * gain
    }
  }
}

// ================= CROSS_INV0: cross-spectrum + irfft pack + inverse stage Ns=1 =================
// 256 threads; thread j of channel c builds Zinv[j+1024r] directly from W1/W2 (naturals + mirrors),
// then does the first inverse radix-32 stage in-register. No LDS, no exchange, ~90 VGPR.
__global__ __launch_bounds__(256) void cross_inv0(const float2* __restrict__ W,
                                                  float2* __restrict__ out0, int cb)
{
  int tid = blockIdx.x*256 + threadIdx.x;
  int c = tid >> 10;
  int j = tid & 1023;
  const float2* W1 = W + (size_t)c * STR;
  const float2* W2 = W + (size_t)(cb + c) * STR;
  const float scale = 1.0f/32768.0f;
  float sj, cj; __sincosf(PI_F*(float)j*(1.0f/32768.0f), &sj, &cj);
  float2 pw = make_float2(cj, sj);                 // e^{+i pi m/32768}, m = j+1024r
  const float2 pstep = make_float2(UC, US);        // e^{+i pi/32}
  float2 v[32];
  #pragma unroll
  for (int r = 0; r < 32; ++r) {
    int m = j + (r << 10);
    int mm = 32768 - m;                            // in [1, 32768]; W[32768] stored
    float2 A  = W1[m],  B  = W2[m];
    float2 Am = W1[mm], Bm = W2[mm];
    float2 Ck = make_float2(A.x*B.x + A.y*B.y,     A.x*B.y - A.y*B.x);     // conj(W1)W2
    float2 Cn = make_float2(Am.x*Bm.x + Am.y*Bm.y, Am.x*Bm.y - Am.y*Bm.x);
    float2 xe = make_float2(0.5f*(Ck.x+Cn.x), 0.5f*(Ck.y-Cn.y));
    float2 d  = make_float2(0.5f*(Ck.x-Cn.x), 0.5f*(Ck.y+Cn.y));
    float2 xo = cmul(pw, d);
    v[r] = make_float2((xe.x - xo.y)*scale, (xe.y + xo.x)*scale);
    pw = cmul(pw, pstep);
  }
  dft32<1>(v);
  float4* o4 = reinterpret_cast<float4*>(out0 + (size_t)c * STR + (size_t)j * 32);
  #pragma unroll
  for (int r = 0; r < 32; r += 2)
    o4[r>>1] = make_float4(v[r].x, v[r].y, v[r+1].x, v[r+1].y);
}

// ---------- inverse final pass (Ns=1024, radix-32), fused unpack + roll + slice ----------
__global__ __launch_bounds__(256) void fft_inv_final32(const float2* __restrict__ in, float* __restrict__ out, int ch0)
{
  int tid = blockIdx.x*256 + threadIdx.x;
  int c = tid >> 10;
  int j = tid & (NBF32-1);
  const float2* src = in + (size_t)c * STR;
  float2 v[32];
  #pragma unroll
  for (int r = 0; r < 32; ++r) v[r] = src[j + (r << 10)];
  float ang = (2.0f*PI_F) * (float)j * (1.0f/32768.0f);
  stage_twiddle32<1>(v, ang);
  dft32<1>(v);
  float* o = out + (size_t)(ch0 + c) * XCOR;
  #pragma unroll
  for (int r = 0; r < 32; ++r) {
    int n = j + (r << 10);
    int m = 2*n;
    int j1 = (m <= 29999) ? (m + 29999) : ((m >= 35537) ? (m - 35537) : -1);
    if (j1 >= 0) o[j1] = v[r].x;
    int m2 = m + 1;
    int j2 = (m2 <= 29999) ? (m2 + 29999) : ((m2 >= 35537) ? (m2 - 35537) : -1);
    if (j2 >= 0) o[j2] = v[r].y;
  }
}

__global__ void diag_kernel(float* out, float vv){ if (threadIdx.x==0 && blockIdx.x==0) out[0] = vv; }

extern "C" void kernel_launch(void* const* d_in, const int* in_sizes, int n_in,
                              void* d_out, int out_size, void* d_ws, size_t ws_size,
                              hipStream_t stream)
{
  const float* d1 = (const float*)d_in[0];
  const float* d2 = (const float*)d_in[1];
  float* out = (float*)d_out;

  const size_t bytesPerCh = 2ULL * 2ULL * (size_t)STR * sizeof(float2);
  int CB = (int)(ws_size / bytesPerCh);
  if (CB > NCH) CB = NCH;
  if (CB < 1) { diag_kernel<<<1,1,0,stream>>>(out, (float)ws_size); return; }

  float2* bufA = (float2*)d_ws;
  float2* bufB = bufA + (size_t)2 * CB * STR;

  for (int ch0 = 0; ch0 < NCH; ch0 += CB) {
    int cb = (NCH - ch0 < CB) ? (NCH - ch0) : CB;
    int nch2 = 2*cb;
    dim3 thr(256);

    // forward stages LG=0, LG=5 (both arrays batched): inputs -> A -> B
    fft_fwd_p1_r32    <<<dim3(nch2*4), thr, 0, stream>>>(d1, d2, bufA, cb, ch0);
    fft_pass32<5,-1>  <<<dim3(nch2*4), thr, 0, stream>>>(bufA, bufB);

    // fused: final fwd stage (LG=10) + unpack + whiten + taper, in place on B
    whiten3           <<<dim3(nch2), dim3(1024), 0, stream>>>(bufB);

    // fused: cross-spectrum + irfft pack + inverse stage LG=0: B -> A
    cross_inv0        <<<dim3(cb*4), thr, 0, stream>>>(bufB, bufA, cb);

    // inverse: middle pass LG=5 (A -> B), final LG=10 fused with roll + slice (B -> out)
    fft_pass32<5,1>   <<<dim3(cb*4), thr, 0, stream>>>(bufA, bufB);
    fft_inv_final32   <<<dim3(cb*4), thr, 0, stream>>>(bufB, out, ch0);
  }
}

// Round 6
// 1717.348 us; speedup vs baseline: 1.3700x; 1.0244x over previous
//
#include <hip/hip_runtime.h>

#define PI_F 3.14159265358979323846f

#define NCH   1000
#define NPTS  30000
#define NHALF 15000      // NPTS/2 packed complex samples
#define NFFT  32768      // complex FFT length (real length 65536)
#define NBF32 1024       // butterflies per channel per radix-32 pass (NFFT/32)
#define STR   32770      // per-channel stride in complex elements
#define XCOR  59999

__device__ __forceinline__ float2 cadd(float2 a, float2 b){ return make_float2(a.x+b.x, a.y+b.y); }
__device__ __forceinline__ float2 csub(float2 a, float2 b){ return make_float2(a.x-b.x, a.y-b.y); }
__device__ __forceinline__ float2 cmul(float2 a, float2 b){ return make_float2(a.x*b.x - a.y*b.y, a.x*b.y + a.y*b.x); }

template<int S>
__device__ __forceinline__ float2 mulIs(float2 z){ return make_float2(-(float)S*z.y, (float)S*z.x); }

// 8-point DFT, ω = e^{S*2πi/8}
template<int S>
__device__ __forceinline__ void dft8(float2 v[8]){
  const float r2 = 0.7071067811865476f;
  const float sf = (float)S;
  float2 ea=cadd(v[0],v[4]), eb=csub(v[0],v[4]);
  float2 ec=cadd(v[2],v[6]), ed=csub(v[2],v[6]);
  float2 oa=cadd(v[1],v[5]), ob=csub(v[1],v[5]);
  float2 oc=cadd(v[3],v[7]), od=csub(v[3],v[7]);
  float2 ied=mulIs<S>(ed), iod=mulIs<S>(od);
  float2 E0=cadd(ea,ec), E2=csub(ea,ec), E1=cadd(eb,ied), E3=csub(eb,ied);
  float2 O0=cadd(oa,oc), O2=csub(oa,oc), O1=cadd(ob,iod), O3=csub(ob,iod);
  float2 T1 = make_float2(r2*(O1.x - sf*O1.y), r2*(O1.y + sf*O1.x));
  float2 T2 = mulIs<S>(O2);
  float2 T3 = make_float2(r2*(-O3.x - sf*O3.y), r2*(sf*O3.x - O3.y));
  v[0]=cadd(E0,O0); v[4]=csub(E0,O0);
  v[1]=cadd(E1,T1); v[5]=csub(E1,T1);
  v[2]=cadd(E2,T2); v[6]=csub(E2,T2);
  v[3]=cadd(E3,T3); v[7]=csub(E3,T3);
}

template<int S>
__device__ __forceinline__ void dft4(float2 v[4]){
  float2 t0=cadd(v[0],v[2]), t1=csub(v[0],v[2]);
  float2 t2=cadd(v[1],v[3]), t3=mulIs<S>(csub(v[1],v[3]));
  v[0]=cadd(t0,t2); v[2]=csub(t0,t2);
  v[1]=cadd(t1,t3); v[3]=csub(t1,t3);
}

// 32-point DFT in registers
template<int S>
__device__ __forceinline__ void dft32(float2 v[32]){
  constexpr float TC[22] = {
    1.f, 0.98078528040323044f, 0.92387953251128674f, 0.83146961230254524f,
    0.70710678118654757f, 0.55557023301960218f, 0.38268343236508978f, 0.19509032201612825f,
    0.f, -0.19509032201612825f, -0.38268343236508978f, -0.55557023301960218f,
    -0.70710678118654757f, -0.83146961230254524f, -0.92387953251128674f, -0.98078528040323044f,
    -1.f, -0.98078528040323044f, -0.92387953251128674f, -0.83146961230254524f,
    -0.70710678118654757f, -0.55557023301960218f };
  constexpr float TS[22] = {
    0.f, 0.19509032201612825f, 0.38268343236508978f, 0.55557023301960218f,
    0.70710678118654757f, 0.83146961230254524f, 0.92387953251128674f, 0.98078528040323044f,
    1.f, 0.98078528040323044f, 0.92387953251128674f, 0.83146961230254524f,
    0.70710678118654757f, 0.55557023301960218f, 0.38268343236508978f, 0.19509032201612825f,
    0.f, -0.19509032201612825f, -0.38268343236508978f, -0.55557023301960218f,
    -0.70710678118654757f, -0.83146961230254524f };
  float2 y[4][8];
  #pragma unroll
  for (int b = 0; b < 4; ++b)
    #pragma unroll
    for (int a = 0; a < 8; ++a) y[b][a] = v[4*a + b];
  #pragma unroll
  for (int b = 0; b < 4; ++b) dft8<S>(y[b]);
  #pragma unroll
  for (int b = 1; b < 4; ++b)
    #pragma unroll
    for (int k1 = 1; k1 < 8; ++k1) {
      int m = b*k1;
      float2 w = make_float2(TC[m], (float)S * TS[m]);
      y[b][k1] = cmul(y[b][k1], w);
    }
  #pragma unroll
  for (int k1 = 0; k1 < 8; ++k1) {
    float2 z[4] = { y[0][k1], y[1][k1], y[2][k1], y[3][k1] };
    dft4<S>(z);
    #pragma unroll
    for (int k2 = 0; k2 < 4; ++k2) v[k1 + 8*k2] = z[k2];
  }
}

template<int S>
__device__ __forceinline__ void stage_twiddle32(float2 v[32], float ang){
  float s1,c1,s8,c8;
  __sincosf(ang, &s1, &c1);
  __sincosf(8.f*ang, &s8, &c8);
  float2 w1 = make_float2(c1, s1), w8 = make_float2(c8, s8);
  float2 w16 = cmul(w8, w8), w24 = cmul(w16, w8);
  float2 base[4] = { make_float2(1.f, 0.f), w8, w16, w24 };
  #pragma unroll
  for (int m = 0; m < 4; ++m) {
    float2 wr = base[m];
    if (m > 0) v[8*m] = cmul(v[8*m], wr);
    #pragma unroll
    for (int l = 1; l < 8; ++l) { wr = cmul(wr, w1); v[8*m+l] = cmul(v[8*m+l], wr); }
  }
}

// ---------- forward pass 1 (Ns=1, radix-32), fused with real-pair packing + zero pad ----------
__global__ __launch_bounds__(256) void fft_fwd_p1_r32(const float* __restrict__ d1, const float* __restrict__ d2,
                                                      float2* __restrict__ out, int cb, int ch0)
{
  int tid = blockIdx.x*256 + threadIdx.x;
  int c = tid >> 10;
  int j = tid & (NBF32-1);
  const float* src = (c < cb) ? (d1 + (size_t)(ch0 + c) * NPTS)
                              : (d2 + (size_t)(ch0 + c - cb) * NPTS);
  const float2* src2 = reinterpret_cast<const float2*>(src);
  float2 v[32];
  #pragma unroll
  for (int r = 0; r < 32; ++r) {
    int m = j + (r << 10);
    v[r] = (m < NHALF) ? src2[m] : make_float2(0.f, 0.f);
  }
  dft32<-1>(v);
  float2* dst = out + (size_t)c * STR + (size_t)j * 32;
  #pragma unroll
  for (int r = 0; r < 32; r += 2)
    *reinterpret_cast<float4*>(dst + r) = make_float4(v[r].x, v[r].y, v[r+1].x, v[r+1].y);
}

// ---------- generic Stockham radix-32 pass, Ns = 2^LG ----------
template<int LG, int S>
__global__ __launch_bounds__(256) void fft_pass32(const float2* __restrict__ in, float2* __restrict__ out)
{
  int tid = blockIdx.x*256 + threadIdx.x;
  int c = tid >> 10;
  int j = tid & (NBF32-1);
  const float2* src = in + (size_t)c * STR;
  float2 v[32];
  #pragma unroll
  for (int r = 0; r < 32; ++r) v[r] = src[j + (r << 10)];
  constexpr int NS = 1 << LG;
  int jm = j & (NS - 1);
  if constexpr (LG > 0) {
    float ang = (float)S * (2.0f*PI_F) * (float)jm / (float)(NS*32);
    stage_twiddle32<S>(v, ang);
  }
  dft32<S>(v);
  int idxD = ((j >> LG) << (LG+5)) + jm;
  float2* dst = out + (size_t)c * STR + idxD;
  #pragma unroll
  for (int r = 0; r < 32; ++r) dst[(size_t)(r << LG)] = v[r];
}

// ================= WHITEN_MEGA =================
// One block (512 thr) per channel. Thread t owns butterfly PAIR (t, 1024-t)  [t=0: combs 0 and 512].
// zA = Z[1024i + t], zB = Z[1024i + (1024-t)] held in registers (final fwd stage done in-thread).
// Every rfft pair (k, 32768-k) is thread-local -> no exchange. Mags -> LDS scan -> gains.
// Array 1: whitened W1 -> global scratch. Array 2: W2 stays in slots; cross C=conj(W1)W2,
// irfft pack, inverse stage-0 dft32, write stage-0 output. Replaces whiten3 + cross_inv0.

__device__ __forceinline__ int pad64(int m){ return m + (m >> 6); }
__device__ __forceinline__ float cmag(float2 a){ return sqrtf(a.x*a.x + a.y*a.y); }
__device__ __forceinline__ float2 conjmul(float2 a, float2 b){  // conj(a)*b
  return make_float2(a.x*b.x + a.y*b.y, a.x*b.y - a.y*b.x);
}

__device__ __forceinline__ float smooth_at64(int k, const float* s, float a0, float alast){
  int hi = k + 327; if (hi > 32768) hi = 32768;
  int lo = k - 328;
  float Shi = s[pad64(hi)];
  float Slo = (lo >= 0) ? s[pad64(lo)] : 0.f;
  float lc = (k < 327) ? (float)(327 - k) : 0.f;
  float rc = (k > 32441) ? (float)(k - 32441) : 0.f;
  return (lc*a0 + (Shi - Slo) + rc*alast) * (1.0f/655.0f);
}

__device__ __forceinline__ float gain_at(int k, const float* s, float a0, float alast){
  float sm = smooth_at64(k, s, a0, alast);
  float tp = 1.0f;
  if (k < 131)         { float sn = __sinf((float)k*(PI_F/260.0f));           tp = sn*sn; }
  else if (k >= 13108) { float cs = __cosf((float)(k-13108)*(PI_F/39320.0f)); tp = cs*cs; }
  return (sm > 0.f) ? tp/sm : 0.f;
}

__device__ __forceinline__ void unpack_pair(float2 zk, float2 zm, int k, float2& Xn, float2& Xm){
  float2 xe = make_float2(0.5f*(zk.x+zm.x), 0.5f*(zk.y-zm.y));
  float2 xh = make_float2(0.5f*(zk.x-zm.x), 0.5f*(zk.y+zm.y));
  float2 xo = make_float2(xh.y, -xh.x);
  float sw, cw; __sincosf(-PI_F*(float)k*(1.0f/32768.0f), &sw, &cw);
  float2 pr = cmul(make_float2(cw, sw), xo);
  Xn = make_float2(xe.x+pr.x, xe.y+pr.y);          // X[k]
  Xm = make_float2(xe.x-pr.x, -(xe.y-pr.y));       // X[32768-k]
}

__device__ __forceinline__ float2 pack_zinv(float2 Ck, float2 Cm, float2 pw){
  const float scale = 1.0f/32768.0f;
  float2 xe = make_float2(0.5f*(Ck.x+Cm.x), 0.5f*(Ck.y-Cm.y));
  float2 d  = make_float2(0.5f*(Ck.x-Cm.x), 0.5f*(Ck.y+Cm.y));
  float2 xo = cmul(pw, d);
  return make_float2((xe.x - xo.y)*scale, (xe.y + xo.x)*scale);
}

__device__ __forceinline__ void load_comb(float2 z[32], const float2* __restrict__ src, int j){
  #pragma unroll
  for (int r = 0; r < 32; ++r) z[r] = src[j + (r<<10)];
  stage_twiddle32<-1>(z, -(2.0f*PI_F)*(float)j*(1.0f/32768.0f));
  dft32<-1>(z);
}

// MODE 0: mags -> s ; MODE 1: gains -> W1 global ; MODE 2: gains -> slots (W2) + x32768
template<int MODE>
__device__ __forceinline__ void pair_sweep(float2 zA[32], float2 zB[32], int t,
                                           float* s, float2* __restrict__ W1, float2* x32768)
{
  float a0 = 0.f, alast = 0.f;
  if (MODE != 0) { a0 = s[0]; alast = s[33280] - s[33278]; }
  if (t != 0) {
    #pragma unroll
    for (int i = 0; i < 32; ++i) {
      int k = (i<<10) + t, km = 32768 - k;
      float2 Xn, Xm; unpack_pair(zA[i], zB[31-i], k, Xn, Xm);
      if (MODE == 0) { s[pad64(k)] = cmag(Xn); s[pad64(km)] = cmag(Xm); }
      else {
        float gn = gain_at(k,  s, a0, alast);
        float gm = gain_at(km, s, a0, alast);
        float2 wn = make_float2(Xn.x*gn, Xn.y*gn);
        float2 wm = make_float2(Xm.x*gm, Xm.y*gm);
        if (MODE == 1) { W1[k] = wn; W1[km] = wm; }
        else { zA[i] = wn; zB[31-i] = wm; }
      }
    }
  } else {
    // comb 0 in zA: pairs (i, 32-i); specials i=0 (k=0 <-> bin 32768), i=16 (k=16384 self)
    #pragma unroll
    for (int i = 0; i <= 16; ++i) {
      int k = i<<10;
      float2 zm = zA[(32-i)&31];
      float2 Xn, Xm; unpack_pair(zA[i], zm, k, Xn, Xm);
      if (MODE == 0) {
        s[pad64(k)] = cmag(Xn);
        if (i == 0) s[pad64(32768)] = cmag(Xm);
        else if (i < 16) s[pad64((32-i)<<10)] = cmag(Xm);
      } else {
        float gn = gain_at(k, s, a0, alast);
        float2 wn = make_float2(Xn.x*gn, Xn.y*gn);
        if (i == 0) {
          float gm = gain_at(32768, s, a0, alast);
          float2 wm = make_float2(Xm.x*gm, Xm.y*gm);
          if (MODE == 1) { W1[0] = wn; W1[32768] = wm; }
          else { zA[0] = wn; *x32768 = wm; }
        } else if (i < 16) {
          int km = (32-i)<<10;
          float gm = gain_at(km, s, a0, alast);
          float2 wm = make_float2(Xm.x*gm, Xm.y*gm);
          if (MODE == 1) { W1[k] = wn; W1[km] = wm; }
          else { zA[i] = wn; zA[32-i] = wm; }
        } else {  // i == 16
          if (MODE == 1) W1[16384] = wn; else zA[16] = wn;
        }
      }
    }
    // comb 512 in zB: pairs (i, 31-i)
    #pragma unroll
    for (int i = 0; i < 16; ++i) {
      int k = (i<<10) + 512, km = 32768 - k;
      float2 Xn, Xm; unpack_pair(zB[i], zB[31-i], k, Xn, Xm);
      if (MODE == 0) { s[pad64(k)] = cmag(Xn); s[pad64(km)] = cmag(Xm); }
      else {
        float gn = gain_at(k,  s, a0, alast);
        float gm = gain_at(km, s, a0, alast);
        float2 wn = make_float2(Xn.x*gn, Xn.y*gn);
        float2 wm = make_float2(Xm.x*gm, Xm.y*gm);
        if (MODE == 1) { W1[k] = wn; W1[km] = wm; }
        else { zB[i] = wn; zB[31-i] = wm; }
      }
    }
  }
}

__device__ __forceinline__ void scan_inclusive(float* s, int t, int lane, int wid, float* wt)
{
  float sum = 0.f;
  #pragma unroll
  for (int q = 0; q < 64; ++q) sum += s[65*t + q];
  if (t == 511) sum += s[33280];
  float vv = sum;
  #pragma unroll
  for (int off = 1; off < 64; off <<= 1) {
    float u = __shfl_up(vv, off);
    if (lane >= off) vv += u;
  }
  if (lane == 63) wt[wid] = vv;
  __syncthreads();
  float wexcl = 0.f;
  #pragma unroll
  for (int w = 0; w < 8; ++w) wexcl += (w < wid) ? wt[w] : 0.f;
  float run = wexcl + (vv - sum);
  #pragma unroll
  for (int q = 0; q < 64; ++q) { float m = s[65*t+q]; run += m; s[65*t+q] = run; }
  if (t == 511) { run += s[33280]; s[33280] = run; }
  __syncthreads();
}

__global__ __launch_bounds__(512) __attribute__((amdgpu_waves_per_eu(2,2)))
void whiten_mega(const float2* __restrict__ F, float2* __restrict__ w1buf,
                 float2* __restrict__ out0, int cb)
{
  const int c = blockIdx.x, t = threadIdx.x;
  const int lane = t & 63, wid = t >> 6;
  __shared__ float s[33281];     // 133.1 KB: mags -> inclusive cumsum (pad every 64)
  __shared__ float wt[8];
  const float2* F1 = F + (size_t)c * STR;
  const float2* F2 = F + (size_t)(cb + c) * STR;
  float2* W1 = w1buf + (size_t)c * STR;
  const int jA = t;
  const int jB = (t == 0) ? 512 : (1024 - t);
  float2 zA[32], zB[32];
  float2 x32768 = make_float2(0.f, 0.f);

  // ---------- array 1: whiten -> W1 (global scratch) ----------
  load_comb(zA, F1, jA);
  load_comb(zB, F1, jB);
  pair_sweep<0>(zA, zB, t, s, W1, &x32768);
  __syncthreads();
  scan_inclusive(s, t, lane, wid, wt);
  pair_sweep<1>(zA, zB, t, s, W1, &x32768);
  __syncthreads();                 // protect s: B1 reads, A2 rewrites

  // ---------- array 2: whiten in regs, cross, pack, inverse stage-0 ----------
  load_comb(zA, F2, jA);
  load_comb(zB, F2, jB);
  pair_sweep<0>(zA, zB, t, s, W1, &x32768);
  __syncthreads();
  scan_inclusive(s, t, lane, wid, wt);
  pair_sweep<2>(zA, zB, t, s, W1, &x32768);

  const float scale = 1.0f/32768.0f;
  if (t != 0) {
    #pragma unroll
    for (int i = 0; i < 32; ++i) {
      int k = (i<<10) + t, km = 32768 - k;
      float2 Ck = conjmul(W1[k],  zA[i]);
      float2 Cm = conjmul(W1[km], zB[31-i]);
      float sp, cp; __sincosf(PI_F*(float)k*(1.0f/32768.0f), &sp, &cp);
      zA[i]    = pack_zinv(Ck, Cm, make_float2(cp, sp));
      zB[31-i] = pack_zinv(Cm, Ck, make_float2(-cp, sp));
    }
  } else {
    // comb 0
    {
      float2 Ck = conjmul(W1[0], zA[0]);
      float2 Cm = conjmul(W1[32768], x32768);
      zA[0] = pack_zinv(Ck, Cm, make_float2(1.f, 0.f));
    }
    #pragma unroll
    for (int i = 1; i < 16; ++i) {
      int k = i<<10, km = 32768 - k;
      float2 Ck = conjmul(W1[k],  zA[i]);
      float2 Cm = conjmul(W1[km], zA[32-i]);
      float sp, cp; __sincosf(PI_F*(float)k*(1.0f/32768.0f), &sp, &cp);
      zA[i]    = pack_zinv(Ck, Cm, make_float2(cp, sp));
      zA[32-i] = pack_zinv(Cm, Ck, make_float2(-cp, sp));
    }
    {
      float2 Ck = conjmul(W1[16384], zA[16]);
      zA[16] = make_float2(Ck.x*scale, -Ck.y*scale);     // Zinv[16384] = conj(C)/N
    }
    // comb 512
    #pragma unroll
    for (int i = 0; i < 16; ++i) {
      int k = (i<<10) + 512, km = 32768 - k;
      float2 Ck = conjmul(W1[k],  zB[i]);
      float2 Cm = conjmul(W1[km], zB[31-i]);
      float sp, cp; __sincosf(PI_F*(float)k*(1.0f/32768.0f), &sp, &cp);
      zB[i]    = pack_zinv(Ck, Cm, make_float2(cp, sp));
      zB[31-i] = pack_zinv(Cm, Ck, make_float2(-cp, sp));
    }
  }

  // inverse Stockham stage Ns=1 for combs jA, jB; write stage-0 output
  dft32<1>(zA);
  dft32<1>(zB);
  float4* oA = reinterpret_cast<float4*>(out0 + (size_t)c*STR + (size_t)jA*32);
  float4* oB = reinterpret_cast<float4*>(out0 + (size_t)c*STR + (size_t)jB*32);
  #pragma unroll
  for (int r = 0; r < 32; r += 2) {
    oA[r>>1] = make_float4(zA[r].x, zA[r].y, zA[r+1].x, zA[r+1].y);
    oB[r>>1] = make_float4(zB[r].x, zB[r].y, zB[r+1].x, zB[r+1].y);
  }
}

// ---------- inverse final pass (Ns=1024, radix-32), fused unpack + roll + slice ----------
__global__ __launch_bounds__(256) void fft_inv_final32(const float2* __restrict__ in, float* __restrict__ out, int ch0)
{
  int tid = blockIdx.x*256 + threadIdx.x;
  int c = tid >> 10;
  int j = tid & (NBF32-1);
  const float2* src = in + (size_t)c * STR;
  float2 v[32];
  #pragma unroll
  for (int r = 0; r < 32; ++r) v[r] = src[j + (r << 10)];
  float ang = (2.0f*PI_F) * (float)j * (1.0f/32768.0f);
  stage_twiddle32<1>(v, ang);
  dft32<1>(v);
  float* o = out + (size_t)(ch0 + c) * XCOR;
  #pragma unroll
  for (int r = 0; r < 32; ++r) {
    int n = j + (r << 10);
    int m = 2*n;
    int j1 = (m <= 29999) ? (m + 29999) : ((m >= 35537) ? (m - 35537) : -1);
    if (j1 >= 0) o[j1] = v[r].x;
    int m2 = m + 1;
    int j2 = (m2 <= 29999) ? (m2 + 29999) : ((m2 >= 35537) ? (m2 - 35537) : -1);
    if (j2 >= 0) o[j2] = v[r].y;
  }
}

__global__ void diag_kernel(float* out, float vv){ if (threadIdx.x==0 && blockIdx.x==0) out[0] = vv; }

extern "C" void kernel_launch(void* const* d_in, const int* in_sizes, int n_in,
                              void* d_out, int out_size, void* d_ws, size_t ws_size,
                              hipStream_t stream)
{
  const float* d1 = (const float*)d_in[0];
  const float* d2 = (const float*)d_in[1];
  float* out = (float*)d_out;

  const size_t bytesPerCh = 2ULL * 2ULL * (size_t)STR * sizeof(float2);
  int CB = (int)(ws_size / bytesPerCh);
  if (CB > NCH) CB = NCH;
  if (CB < 1) { diag_kernel<<<1,1,0,stream>>>(out, (float)ws_size); return; }

  float2* bufA = (float2*)d_ws;
  float2* bufB = bufA + (size_t)2 * CB * STR;

  for (int ch0 = 0; ch0 < NCH; ch0 += CB) {
    int cb = (NCH - ch0 < CB) ? (NCH - ch0) : CB;
    int nch2 = 2*cb;
    dim3 thr(256);

    // forward stages LG=0, LG=5 (both arrays batched): inputs -> A -> B
    fft_fwd_p1_r32    <<<dim3(nch2*4), thr, 0, stream>>>(d1, d2, bufA, cb, ch0);
    fft_pass32<5,-1>  <<<dim3(nch2*4), thr, 0, stream>>>(bufA, bufB);

    // fused: final fwd stage + unpack + whiten (x2) + cross + irfft pack + inverse stage 0
    // reads B (both arrays); W1 scratch in A[cb..2cb); stage-0 output -> A[0..cb)
    whiten_mega       <<<dim3(cb), dim3(512), 0, stream>>>(bufB, bufA + (size_t)cb * STR, bufA, cb);

    // inverse: middle pass LG=5 (A -> B), final LG=10 fused with roll + slice (B -> out)
    fft_pass32<5,1>   <<<dim3(cb*4), thr, 0, stream>>>(bufA, bufB);
    fft_inv_final32   <<<dim3(cb*4), thr, 0, stream>>>(bufB, out, ch0);
  }
}

// Round 7
// 1197.226 us; speedup vs baseline: 1.9652x; 1.4344x over previous
//
#include <hip/hip_runtime.h>

#define PI_F 3.14159265358979323846f

#define NCH   1000
#define NPTS  30000
#define NHALF 15000      // NPTS/2 packed complex samples
#define NFFT  32768      // complex FFT length (real length 65536)
#define NBF32 1024       // butterflies per channel per radix-32 pass (NFFT/32)
#define STR   32770      // per-channel stride in complex elements
#define XCOR  59999

#define UC 0.99518472667219693f
#define US 0.09801714032956060f

__device__ __forceinline__ float2 cadd(float2 a, float2 b){ return make_float2(a.x+b.x, a.y+b.y); }
__device__ __forceinline__ float2 csub(float2 a, float2 b){ return make_float2(a.x-b.x, a.y-b.y); }
__device__ __forceinline__ float2 cmul(float2 a, float2 b){ return make_float2(a.x*b.x - a.y*b.y, a.x*b.y + a.y*b.x); }

template<int S>
__device__ __forceinline__ float2 mulIs(float2 z){ return make_float2(-(float)S*z.y, (float)S*z.x); }

// 8-point DFT, ω = e^{S*2πi/8}
template<int S>
__device__ __forceinline__ void dft8(float2 v[8]){
  const float r2 = 0.7071067811865476f;
  const float sf = (float)S;
  float2 ea=cadd(v[0],v[4]), eb=csub(v[0],v[4]);
  float2 ec=cadd(v[2],v[6]), ed=csub(v[2],v[6]);
  float2 oa=cadd(v[1],v[5]), ob=csub(v[1],v[5]);
  float2 oc=cadd(v[3],v[7]), od=csub(v[3],v[7]);
  float2 ied=mulIs<S>(ed), iod=mulIs<S>(od);
  float2 E0=cadd(ea,ec), E2=csub(ea,ec), E1=cadd(eb,ied), E3=csub(eb,ied);
  float2 O0=cadd(oa,oc), O2=csub(oa,oc), O1=cadd(ob,iod), O3=csub(ob,iod);
  float2 T1 = make_float2(r2*(O1.x - sf*O1.y), r2*(O1.y + sf*O1.x));
  float2 T2 = mulIs<S>(O2);
  float2 T3 = make_float2(r2*(-O3.x - sf*O3.y), r2*(sf*O3.x - O3.y));
  v[0]=cadd(E0,O0); v[4]=csub(E0,O0);
  v[1]=cadd(E1,T1); v[5]=csub(E1,T1);
  v[2]=cadd(E2,T2); v[6]=csub(E2,T2);
  v[3]=cadd(E3,T3); v[7]=csub(E3,T3);
}

template<int S>
__device__ __forceinline__ void dft4(float2 v[4]){
  float2 t0=cadd(v[0],v[2]), t1=csub(v[0],v[2]);
  float2 t2=cadd(v[1],v[3]), t3=mulIs<S>(csub(v[1],v[3]));
  v[0]=cadd(t0,t2); v[2]=csub(t0,t2);
  v[1]=cadd(t1,t3); v[3]=csub(t1,t3);
}

// 32-point DFT in registers
template<int S>
__device__ __forceinline__ void dft32(float2 v[32]){
  constexpr float TC[22] = {
    1.f, 0.98078528040323044f, 0.92387953251128674f, 0.83146961230254524f,
    0.70710678118654757f, 0.55557023301960218f, 0.38268343236508978f, 0.19509032201612825f,
    0.f, -0.19509032201612825f, -0.38268343236508978f, -0.55557023301960218f,
    -0.70710678118654757f, -0.83146961230254524f, -0.92387953251128674f, -0.98078528040323044f,
    -1.f, -0.98078528040323044f, -0.92387953251128674f, -0.83146961230254524f,
    -0.70710678118654757f, -0.55557023301960218f };
  constexpr float TS[22] = {
    0.f, 0.19509032201612825f, 0.38268343236508978f, 0.55557023301960218f,
    0.70710678118654757f, 0.83146961230254524f, 0.92387953251128674f, 0.98078528040323044f,
    1.f, 0.98078528040323044f, 0.92387953251128674f, 0.83146961230254524f,
    0.70710678118654757f, 0.55557023301960218f, 0.38268343236508978f, 0.19509032201612825f,
    0.f, -0.19509032201612825f, -0.38268343236508978f, -0.55557023301960218f,
    -0.70710678118654757f, -0.83146961230254524f };
  float2 y[4][8];
  #pragma unroll
  for (int b = 0; b < 4; ++b)
    #pragma unroll
    for (int a = 0; a < 8; ++a) y[b][a] = v[4*a + b];
  #pragma unroll
  for (int b = 0; b < 4; ++b) dft8<S>(y[b]);
  #pragma unroll
  for (int b = 1; b < 4; ++b)
    #pragma unroll
    for (int k1 = 1; k1 < 8; ++k1) {
      int m = b*k1;
      float2 w = make_float2(TC[m], (float)S * TS[m]);
      y[b][k1] = cmul(y[b][k1], w);
    }
  #pragma unroll
  for (int k1 = 0; k1 < 8; ++k1) {
    float2 z[4] = { y[0][k1], y[1][k1], y[2][k1], y[3][k1] };
    dft4<S>(z);
    #pragma unroll
    for (int k2 = 0; k2 < 4; ++k2) v[k1 + 8*k2] = z[k2];
  }
}

template<int S>
__device__ __forceinline__ void stage_twiddle32(float2 v[32], float ang){
  float s1,c1,s8,c8;
  __sincosf(ang, &s1, &c1);
  __sincosf(8.f*ang, &s8, &c8);
  float2 w1 = make_float2(c1, s1), w8 = make_float2(c8, s8);
  float2 w16 = cmul(w8, w8), w24 = cmul(w16, w8);
  float2 base[4] = { make_float2(1.f, 0.f), w8, w16, w24 };
  #pragma unroll
  for (int m = 0; m < 4; ++m) {
    float2 wr = base[m];
    if (m > 0) v[8*m] = cmul(v[8*m], wr);
    #pragma unroll
    for (int l = 1; l < 8; ++l) { wr = cmul(wr, w1); v[8*m+l] = cmul(v[8*m+l], wr); }
  }
}

// ========== FWD FUSED: stages LG0 + LG5 through LDS (one kernel, one global round-trip) ==========
// Block b (of 4 per array-channel) computes stage-2 (LG5) butterflies j2 in [256b, 256b+256).
// Those need stage-1 (LG0) butterflies j1 in {8b + d + 32r : d<8, r<32} (256 of them).
// Thread t: stage-1 butterfly j1 = 8b + (t&7) + 32*(t>>3), output slot r -> lds[t*33 + r].
// Stage-2 thread t: j2 = 256b+t reads v[r] = lds[((t>>5) + 8r)*33 + (t&31)].
__global__ __launch_bounds__(256) void fft_fwd_fused(const float* __restrict__ d1, const float* __restrict__ d2,
                                                     float2* __restrict__ out, int cb, int ch0)
{
  __shared__ float2 lds[256*33];   // 67.6 KB, stride-33 rows: conflict-free writes
  const int bid = blockIdx.x;
  const int c = bid >> 2, b = bid & 3;
  const int t = threadIdx.x;
  const float* src = (c < cb) ? (d1 + (size_t)(ch0 + c) * NPTS)
                              : (d2 + (size_t)(ch0 + c - cb) * NPTS);
  const float2* src2 = reinterpret_cast<const float2*>(src);

  // ---- stage 1 (LG0, no twiddle), fused real-pair packing + zero pad ----
  const int j1 = 8*b + (t & 7) + 32*(t >> 3);
  float2 v[32];
  #pragma unroll
  for (int r = 0; r < 32; ++r) {
    int m = j1 + (r << 10);
    v[r] = (m < NHALF) ? src2[m] : make_float2(0.f, 0.f);
  }
  dft32<-1>(v);
  #pragma unroll
  for (int r = 0; r < 32; ++r) lds[t*33 + r] = v[r];
  __syncthreads();

  // ---- stage 2 (LG5): j2 = 256b + t ----
  const int d = t >> 5, jm = t & 31;
  #pragma unroll
  for (int r = 0; r < 32; ++r) v[r] = lds[(d + 8*r)*33 + jm];
  stage_twiddle32<-1>(v, -(2.0f*PI_F) * (float)jm * (1.0f/1024.0f));
  dft32<-1>(v);
  const int j2 = 256*b + t;
  float2* dst = out + (size_t)c * STR + ((j2 >> 5) << 10) + jm;
  #pragma unroll
  for (int r = 0; r < 32; ++r) dst[(size_t)(r << 5)] = v[r];
}

// ---------- generic Stockham radix-32 pass, Ns = 2^LG ----------
template<int LG, int S>
__global__ __launch_bounds__(256) void fft_pass32(const float2* __restrict__ in, float2* __restrict__ out)
{
  int tid = blockIdx.x*256 + threadIdx.x;
  int c = tid >> 10;
  int j = tid & (NBF32-1);
  const float2* src = in + (size_t)c * STR;
  float2 v[32];
  #pragma unroll
  for (int r = 0; r < 32; ++r) v[r] = src[j + (r << 10)];
  constexpr int NS = 1 << LG;
  int jm = j & (NS - 1);
  if constexpr (LG > 0) {
    float ang = (float)S * (2.0f*PI_F) * (float)jm / (float)(NS*32);
    stage_twiddle32<S>(v, ang);
  }
  dft32<S>(v);
  int idxD = ((j >> LG) << (LG+5)) + jm;
  float2* dst = out + (size_t)c * STR + idxD;
  #pragma unroll
  for (int r = 0; r < 32; ++r) dst[(size_t)(r << LG)] = v[r];
}

// ---------- whitening (round-2 verified): rfft unpack + running-abs-mean + tapers, in place ----------
__device__ __forceinline__ int padidx(int m){ return m + (m >> 5); }

__global__ __launch_bounds__(1024) void whiten_kernel(float2* __restrict__ buf)
{
  const int ch = blockIdx.x;
  const int t  = threadIdx.x;
  float2* Z = buf + (size_t)ch * STR;
  __shared__ float s[33793];     // 32769 magnitudes, padded every 32
  __shared__ float wsums[16];

  float2 X[33];
  // phase 1: unpack X[k] from Z[k], Z[N-k]; magnitudes to LDS
  #pragma unroll
  for (int i = 0; i < 33; ++i) {
    int k = i*1024 + t;
    if (i < 32 || t == 0) {
      float2 zk = Z[k & (NFFT-1)];
      float2 zn = Z[(NFFT - k) & (NFFT-1)];
      float2 xe = make_float2(0.5f*(zk.x+zn.x), 0.5f*(zk.y-zn.y));
      float2 xh = make_float2(0.5f*(zk.x-zn.x), 0.5f*(zk.y+zn.y)); // (zk-conj(zn))/2
      float2 xo = make_float2(xh.y, -xh.x);                        // /i
      float ang = -PI_F * (float)k * (1.0f/32768.0f);
      float sn, cs; __sincosf(ang, &sn, &cs);
      float2 w = make_float2(cs, sn);
      X[i] = cadd(xe, cmul(w, xo));
      s[padidx(k)] = sqrtf(X[i].x*X[i].x + X[i].y*X[i].y);
    }
  }
  __syncthreads();

  // phase 2: block-wide inclusive cumsum of magnitudes (in place in LDS)
  const int base = t*32;
  float sum = 0.f;
  #pragma unroll
  for (int q = 0; q < 32; ++q) sum += s[padidx(base+q)];
  if (t == 1023) sum += s[padidx(32768)];
  const int lane = t & 63, wid = t >> 6;
  float v = sum;
  #pragma unroll
  for (int off = 1; off < 64; off <<= 1) {
    float u = __shfl_up(v, off);
    if (lane >= off) v += u;
  }
  if (lane == 63) wsums[wid] = v;
  __syncthreads();
  float wexcl = 0.f;
  for (int w = 0; w < 16; ++w) wexcl += (w < wid) ? wsums[w] : 0.f;
  float run = wexcl + (v - sum);       // exclusive prefix of this thread's chunk
  #pragma unroll
  for (int q = 0; q < 32; ++q) {
    int idx = padidx(base+q);
    run += s[idx];
    s[idx] = run;
  }
  if (t == 1023) { int idx = padidx(32768); run += s[idx]; s[idx] = run; }
  __syncthreads();

  // phase 3: smoothed = edge-clamped 655-bin box mean; whiten + taper; write W in place
  const float a0 = s[padidx(0)];
  const float alast = s[padidx(32768)] - s[padidx(32767)];
  #pragma unroll
  for (int i = 0; i < 33; ++i) {
    int k = i*1024 + t;
    if (i < 32 || t == 0) {
      int hi = k + 327; if (hi > 32768) hi = 32768;
      int lom1 = k - 328;
      float Shi = s[padidx(hi)];
      float Slo = (lom1 >= 0) ? s[padidx(lom1)] : 0.f;
      float lc = (k < 327) ? (float)(327 - k) : 0.f;
      float rc = (k > 32441) ? (float)(k - 32441) : 0.f;
      float smoothed = (lc*a0 + (Shi - Slo) + rc*alast) * (1.0f/655.0f);
      float2 wv;
      if (smoothed > 0.f) {
        float inv = 1.0f / smoothed;
        wv = make_float2(X[i].x*inv, X[i].y*inv);
      } else wv = make_float2(0.f, 0.f);
      float tp = 1.0f;
      if (k < 131)        { float th = (float)k * (PI_F/260.0f);           float sn = __sinf(th); tp = sn*sn; }
      else if (k >= 13108){ float th = (float)(k-13108) * (PI_F/39320.0f); float cs = __cosf(th); tp = cs*cs; }
      wv.x *= tp; wv.y *= tp;
      Z[k] = wv;
    }
  }
}

// ================= CROSS_INV0 (round-5 verified): cross-spectrum + irfft pack + inverse stage Ns=1 =================
__global__ __launch_bounds__(256) void cross_inv0(const float2* __restrict__ W,
                                                  float2* __restrict__ out0, int cb)
{
  int tid = blockIdx.x*256 + threadIdx.x;
  int c = tid >> 10;
  int j = tid & 1023;
  const float2* W1 = W + (size_t)c * STR;
  const float2* W2 = W + (size_t)(cb + c) * STR;
  const float scale = 1.0f/32768.0f;
  float sj, cj; __sincosf(PI_F*(float)j*(1.0f/32768.0f), &sj, &cj);
  float2 pw = make_float2(cj, sj);                 // e^{+i pi m/32768}, m = j+1024r
  const float2 pstep = make_float2(UC, US);        // e^{+i pi/32}
  float2 v[32];
  #pragma unroll
  for (int r = 0; r < 32; ++r) {
    int m = j + (r << 10);
    int mm = 32768 - m;                            // in [1, 32768]; W[32768] stored
    float2 A  = W1[m],  B  = W2[m];
    float2 Am = W1[mm], Bm = W2[mm];
    float2 Ck = make_float2(A.x*B.x + A.y*B.y,     A.x*B.y - A.y*B.x);     // conj(W1)W2
    float2 Cn = make_float2(Am.x*Bm.x + Am.y*Bm.y, Am.x*Bm.y - Am.y*Bm.x);
    float2 xe = make_float2(0.5f*(Ck.x+Cn.x), 0.5f*(Ck.y-Cn.y));
    float2 d  = make_float2(0.5f*(Ck.x-Cn.x), 0.5f*(Ck.y+Cn.y));
    float2 xo = cmul(pw, d);
    v[r] = make_float2((xe.x - xo.y)*scale, (xe.y + xo.x)*scale);
    pw = cmul(pw, pstep);
  }
  dft32<1>(v);
  float4* o4 = reinterpret_cast<float4*>(out0 + (size_t)c * STR + (size_t)j * 32);
  #pragma unroll
  for (int r = 0; r < 32; r += 2)
    o4[r>>1] = make_float4(v[r].x, v[r].y, v[r+1].x, v[r+1].y);
}

// ---------- inverse final pass (Ns=1024, radix-32), fused unpack + roll + slice ----------
__global__ __launch_bounds__(256) void fft_inv_final32(const float2* __restrict__ in, float* __restrict__ out, int ch0)
{
  int tid = blockIdx.x*256 + threadIdx.x;
  int c = tid >> 10;
  int j = tid & (NBF32-1);
  const float2* src = in + (size_t)c * STR;
  float2 v[32];
  #pragma unroll
  for (int r = 0; r < 32; ++r) v[r] = src[j + (r << 10)];
  float ang = (2.0f*PI_F) * (float)j * (1.0f/32768.0f);
  stage_twiddle32<1>(v, ang);
  dft32<1>(v);
  float* o = out + (size_t)(ch0 + c) * XCOR;
  #pragma unroll
  for (int r = 0; r < 32; ++r) {
    int n = j + (r << 10);
    int m = 2*n;
    int j1 = (m <= 29999) ? (m + 29999) : ((m >= 35537) ? (m - 35537) : -1);
    if (j1 >= 0) o[j1] = v[r].x;
    int m2 = m + 1;
    int j2 = (m2 <= 29999) ? (m2 + 29999) : ((m2 >= 35537) ? (m2 - 35537) : -1);
    if (j2 >= 0) o[j2] = v[r].y;
  }
}

__global__ void diag_kernel(float* out, float vv){ if (threadIdx.x==0 && blockIdx.x==0) out[0] = vv; }

extern "C" void kernel_launch(void* const* d_in, const int* in_sizes, int n_in,
                              void* d_out, int out_size, void* d_ws, size_t ws_size,
                              hipStream_t stream)
{
  const float* d1 = (const float*)d_in[0];
  const float* d2 = (const float*)d_in[1];
  float* out = (float*)d_out;

  const size_t bytesPerCh = 2ULL * 2ULL * (size_t)STR * sizeof(float2);
  int CB = (int)(ws_size / bytesPerCh);
  if (CB > NCH) CB = NCH;
  if (CB < 1) { diag_kernel<<<1,1,0,stream>>>(out, (float)ws_size); return; }

  float2* bufA = (float2*)d_ws;
  float2* bufB = bufA + (size_t)2 * CB * STR;

  for (int ch0 = 0; ch0 < NCH; ch0 += CB) {
    int cb = (NCH - ch0 < CB) ? (NCH - ch0) : CB;
    int nch2 = 2*cb;
    dim3 thr(256);

    // forward: fused stages LG0+LG5 (inputs -> A), then LG10 -> natural-order Z (A -> B)
    fft_fwd_fused     <<<dim3(nch2*4), thr, 0, stream>>>(d1, d2, bufA, cb, ch0);
    fft_pass32<10,-1> <<<dim3(nch2*4), thr, 0, stream>>>(bufA, bufB);

    // whiten in place on natural-order Z (B)
    whiten_kernel     <<<dim3(nch2), dim3(1024), 0, stream>>>(bufB);

    // cross-spectrum + irfft pack + inverse stage-0: B -> A
    cross_inv0        <<<dim3(cb*4), thr, 0, stream>>>(bufB, bufA, cb);

    // inverse: middle pass LG=5 (A -> B), final LG=10 fused with roll + slice (B -> out)
    fft_pass32<5,1>   <<<dim3(cb*4), thr, 0, stream>>>(bufA, bufB);
    fft_inv_final32   <<<dim3(cb*4), thr, 0, stream>>>(bufB, out, ch0);
  }
}